// Round 2
// baseline (87.845 us; speedup 1.0000x reference)
//
#include <hip/hip_runtime.h>

// Problem constants (from reference setup_inputs)
#define B_   8
#define CIN  3
#define OC   16
#define HH   128
#define WW   128
#define KK   3
#define FF   27              // CIN*KK*KK
#define NSITE (B_*HH*WW)     // 131072 output pixel-sites
#define OGRP 4               // output channels per block (2 packed pairs)
#define NWCOL (2*FF)         // 54 packed word-columns
#define MBLK 512             // main-kernel block size

// ---------------------------------------------------------------------------
// Prep kernel: builds
//  (1) transposed product table T[b*256+a] = hi*256+(lo&255) of lut[a*256+b]
//      (transposed so LDS gathers on the random activation byte 'a' spread
//       across banks),
//  (2) qa = clip(rint(x/sx)) + 128 as uint8,
//  (3) qwb = clip(rint(w/sw)) + 128.
// rintf = nearest-even = np.round; IEEE f32 divide → bit-exact vs numpy.
// ---------------------------------------------------------------------------
__global__ void prep_kernel(const float* __restrict__ x,
                            const float* __restrict__ wgt,
                            const float* __restrict__ sx_p,
                            const float* __restrict__ sw_p,
                            const int*   __restrict__ lut,
                            short*       __restrict__ T,
                            int*         __restrict__ qwb,
                            unsigned char* __restrict__ qa)
{
    int i = blockIdx.x * blockDim.x + threadIdx.x;

    if (i < 65536) {
        int b = i >> 8, a = i & 255;
        int r = (a << 8) | b;                 // original lut row = ip*256 + iw
        int hi = lut[2 * r];
        int lo = lut[2 * r + 1] & 255;
        T[i] = (short)(hi * 256 + lo);        // fits int16: [-32512, 32767]
    }
    if (i < B_ * CIN * HH * WW) {
        float q = rintf(x[i] / sx_p[0]);
        q = fminf(127.f, fmaxf(-127.f, q));
        qa[i] = (unsigned char)((int)q + 128);   // ip in [1,255]
    }
    if (i < OC * FF) {
        float q = rintf(wgt[i] / sw_p[0]);
        q = fminf(127.f, fmaxf(-127.f, q));
        qwb[i] = (int)q + 128;                   // iw in [1,255]
    }
}

// ---------------------------------------------------------------------------
// Main kernel: block = (512 sites) x (4 output channels as 2 packed pairs).
// LDS holds 54 word-columns: col32[(p*27+f)*256 + a] packs the int16 LUT
// products of channel pair (2p, 2p+1) for weight slot f, activation byte a.
//   gather:  u = ds_read_b32(av4[f] + imm);  acc_lo += sext16(u); acc_hi += u>>16
// -> 54 DS + ~8 VALU per site per group for 4 channels (was 108 DS).
// Staging: thread t -> a = t&255 (stride-1 LDS writes, conflict-free),
// ph = t>>8 (wave-uniform -> qwb reads become scalar loads), loop f=0..26.
// 54 KB LDS -> 2 blocks/CU resident, 16 waves/CU.
// ---------------------------------------------------------------------------
__global__ __launch_bounds__(MBLK, 4) void conv_kernel(
    const unsigned char* __restrict__ qa,
    const int*   __restrict__ qwb,
    const short* __restrict__ T,
    const float* __restrict__ bias,
    const float* __restrict__ sx_p,
    const float* __restrict__ sw_p,
    float*       __restrict__ out)
{
    __shared__ unsigned int col32[NWCOL * 256];   // 55296 B

    const int og   = blockIdx.x & 3;    // output-channel group (4 ch)
    const int sblk = blockIdx.x >> 2;   // site block

    // ---- stage packed columns ----
    {
        const int a  = threadIdx.x & 255;
        const int ph = threadIdx.x >> 8;          // 0/1, wave-uniform
        const int o0 = og * OGRP + ph * 2;
        #pragma unroll
        for (int f = 0; f < FF; ++f) {
            int v0 = qwb[o0 * FF + f];            // scalar loads (uniform)
            int v1 = qwb[(o0 + 1) * FF + f];
            unsigned int w0 = (unsigned short)T[(v0 << 8) | a];
            unsigned int w1 = (unsigned short)T[(v1 << 8) | a];
            col32[(ph * FF + f) * 256 + a] = w0 | (w1 << 16);
        }
    }
    __syncthreads();

    const int s  = sblk * MBLK + threadIdx.x;   // site id, exact grid
    const int b  = s >> 14;
    const int hw = s & 16383;
    const int h  = hw >> 7;
    const int w  = hw & 127;

    // ---- load 3x3x3 patch; zero-pad => qx=0 => a=128. Keep a*4 (byte addr). ----
    int av4[FF];
    #pragma unroll
    for (int c = 0; c < CIN; ++c) {
        const unsigned char* base = qa + (b * CIN + c) * (HH * WW);
        #pragma unroll
        for (int kh = 0; kh < KK; ++kh) {
            int hh2 = h + kh - 1;
            #pragma unroll
            for (int kw = 0; kw < KK; ++kw) {
                int ww2 = w + kw - 1;
                int a = 128;
                if ((unsigned)hh2 < HH && (unsigned)ww2 < WW)
                    a = base[hh2 * WW + ww2];
                av4[c * 9 + kh * 3 + kw] = a << 2;
            }
        }
    }

    // ---- gather-accumulate: 2 DS words per f serve all 4 channels ----
    int acc0 = 0, acc1 = 0, acc2 = 0, acc3 = 0;
    #pragma unroll
    for (int f = 0; f < FF; ++f) {
        const unsigned int* p =
            (const unsigned int*)((const char*)col32 + av4[f]);
        unsigned int u0 = p[f * 256];             // pair 0, imm offset f*1024
        unsigned int u1 = p[f * 256 + FF * 256];  // pair 1, imm +27648
        acc0 += (int)(short)(u0 & 0xFFFF);
        acc1 += ((int)u0) >> 16;
        acc2 += (int)(short)(u1 & 0xFFFF);
        acc3 += ((int)u1) >> 16;
    }

    const float sxw = sx_p[0] * sw_p[0];
    const int o0 = og * OGRP;
    float r0 = (float)acc0 * sxw + bias[o0];
    float r1 = (float)acc1 * sxw + bias[o0 + 1];
    float r2 = (float)acc2 * sxw + bias[o0 + 2];
    float r3 = (float)acc3 * sxw + bias[o0 + 3];
    const int sidx = (b * OC * HH + h) * WW + w;    // + o*HH*WW per channel
    out[sidx + (o0    ) * HH * WW] = r0;
    out[sidx + (o0 + 1) * HH * WW] = r1;
    out[sidx + (o0 + 2) * HH * WW] = r2;
    out[sidx + (o0 + 3) * HH * WW] = r3;
}

// ---------------------------------------------------------------------------
// d_in order: x, weight, bias, scale_x, scale_w, lut
// ws layout: T (131072 B) | qwb (1728 B, padded to 2048) | qa (393216 B)
// ---------------------------------------------------------------------------
extern "C" void kernel_launch(void* const* d_in, const int* in_sizes, int n_in,
                              void* d_out, int out_size, void* d_ws, size_t ws_size,
                              hipStream_t stream)
{
    const float* x    = (const float*)d_in[0];
    const float* wgt  = (const float*)d_in[1];
    const float* bias = (const float*)d_in[2];
    const float* sx   = (const float*)d_in[3];
    const float* sw   = (const float*)d_in[4];
    const int*   lut  = (const int*)d_in[5];

    char* ws = (char*)d_ws;
    short* T           = (short*)ws;                           // 131072 B
    int* qwb           = (int*)(ws + 131072);                  // 1728 B
    unsigned char* qa  = (unsigned char*)(ws + 131072 + 2048); // 393216 B

    // prep: 393216 threads covers qa (largest job); T and qwb are subsets
    prep_kernel<<<(B_ * CIN * HH * WW) / 256, 256, 0, stream>>>(
        x, wgt, sx, sw, lut, T, qwb, qa);

    // main: 256 site-blocks x 4 channel-groups = 1024 blocks
    conv_kernel<<<(NSITE / MBLK) * 4, MBLK, 0, stream>>>(
        qa, qwb, T, bias, sx, sw, (float*)d_out);
}